// Round 3
// baseline (395.395 us; speedup 1.0000x reference)
//
#include <hip/hip_runtime.h>
#include <math.h>

#define SEQ 2048
#define DIM 1024
#define NH 16

typedef short s8v __attribute__((ext_vector_type(8)));
typedef float f4v __attribute__((ext_vector_type(4)));

__device__ __forceinline__ unsigned short f2bf(float x) {   // RNE
    unsigned u = __float_as_uint(x);
    u += 0x7FFFu + ((u >> 16) & 1u);
    return (unsigned short)(u >> 16);
}
__device__ __forceinline__ unsigned cvt_pk_bf16(float lo, float hi) {
    unsigned r;
    asm("v_cvt_pk_bf16_f32 %0, %1, %2" : "=v"(r) : "v"(lo), "v"(hi));
    return r;
}
// Full-rate exp2: v_exp_f32 is ~30 cyc/wave (1/16 rate, derived from VALUBusy r2).
// rndne split + degree-4 Taylor on [-0.5,0.5] (rel err < 5e-5) + v_ldexp_f32.
// ~8 full-rate VALU ops ~= 16 cyc/wave.
__device__ __forceinline__ float fast_exp2(float x) {
    float r = __builtin_rintf(x);          // v_rndne_f32
    float f = x - r;                       // v_sub_f32
    int   e = (int)r;                      // v_cvt_i32_f32 (r is integral)
    float p = fmaf(f, 0.0096181291f, 0.0555041087f);
    p = fmaf(f, p, 0.2402265069f);
    p = fmaf(f, p, 0.6931471806f);
    p = fmaf(f, p, 1.0f);
    return ldexpf(p, e);                   // v_ldexp_f32
}

// ---------------- q,k,v fp32 -> bf16 (one launch) ----------------
__global__ void conv3_f32_bf16(const float* __restrict__ q, const float* __restrict__ k,
                               const float* __restrict__ v,
                               unsigned short* __restrict__ qb, unsigned short* __restrict__ kb,
                               unsigned short* __restrict__ vb, int n4) {
    const float* in = (blockIdx.y == 0) ? q : (blockIdx.y == 1) ? k : v;
    unsigned short* out = (blockIdx.y == 0) ? qb : (blockIdx.y == 1) ? kb : vb;
    int i = blockIdx.x * 256 + threadIdx.x;
    if (i >= n4) return;
    float4 x = ((const float4*)in)[i];
    ushort4 o;
    o.x = f2bf(x.x); o.y = f2bf(x.y); o.z = f2bf(x.z); o.w = f2bf(x.w);
    ((ushort4*)out)[i] = o;
}

// ---------------- 4x W[K,N] fp32 -> WT[N,K] bf16 (one launch) ----------------
__global__ __launch_bounds__(256)
void convT4_f32_bf16(const float* __restrict__ W0, const float* __restrict__ W1,
                     const float* __restrict__ W2, const float* __restrict__ W3,
                     unsigned short* __restrict__ T0, unsigned short* __restrict__ T1,
                     unsigned short* __restrict__ T2, unsigned short* __restrict__ T3) {
    const float* W = (blockIdx.z == 0) ? W0 : (blockIdx.z == 1) ? W1 : (blockIdx.z == 2) ? W2 : W3;
    unsigned short* WT = (blockIdx.z == 0) ? T0 : (blockIdx.z == 1) ? T1 : (blockIdx.z == 2) ? T2 : T3;
    __shared__ float T[64][65];
    const int t = threadIdx.x;
    const int n0 = blockIdx.x * 64, k0 = blockIdx.y * 64;
    #pragma unroll
    for (int i = 0; i < 4; i++) {
        int idx = t + i * 256;
        int r = idx >> 4, c4 = idx & 15;
        float4 v = *(const float4*)&W[(size_t)(k0 + r) * DIM + n0 + c4 * 4];
        T[r][c4 * 4 + 0] = v.x; T[r][c4 * 4 + 1] = v.y;
        T[r][c4 * 4 + 2] = v.z; T[r][c4 * 4 + 3] = v.w;
    }
    __syncthreads();
    #pragma unroll
    for (int i = 0; i < 4; i++) {
        int idx = t + i * 256;
        int rn = idx >> 4, c4 = idx & 15;
        ushort4 o;
        o.x = f2bf(T[c4 * 4 + 0][rn]);
        o.y = f2bf(T[c4 * 4 + 1][rn]);
        o.z = f2bf(T[c4 * 4 + 2][rn]);
        o.w = f2bf(T[c4 * 4 + 3][rn]);
        *(ushort4*)&WT[(size_t)(n0 + rn) * DIM + k0 + c4 * 4] = o;
    }
}

// ---------------- GEMM core (m97 staging), shared by qkv+out projections ----------
// C = A[M,K]*BT[N,K]^T + bias. 128x128 tile, BK=64, global_load_lds staging.
// MODE 0: fp32 out [M,DIM]; MODE 1: bf16 head-split [B,NH,SEQ,64] * scale;
// MODE 2: bf16 head-split TRANSPOSED [B*NH][64][SEQ] (fused V transpose).
template<int MODE>
__device__ __forceinline__
void gemm_core(const unsigned short* __restrict__ A,
               const unsigned short* __restrict__ BT,
               const float* __restrict__ bias, void* __restrict__ outp,
               float scale, int bx, int by)
{
    __shared__ __align__(16) unsigned short As[128 * 64];
    __shared__ __align__(16) unsigned short Bs[128 * 64];
    const int t = threadIdx.x;
    const int lane = t & 63, w = t >> 6;
    const int l15 = lane & 15, quad = lane >> 4;
    const int bm = by * 128, bn = bx * 128;
    const int wm = (w & 1) * 64, wn = (w >> 1) * 64;
    const int lrow = lane >> 3, lcol = (lane & 7) * 8;

    f4v acc[4][4];
    #pragma unroll
    for (int mi = 0; mi < 4; mi++)
        #pragma unroll
        for (int ni = 0; ni < 4; ni++)
            acc[mi][ni] = (f4v){0.f, 0.f, 0.f, 0.f};

    for (int k0 = 0; k0 < DIM; k0 += 64) {
        __syncthreads();
        #pragma unroll
        for (int i = 0; i < 4; i++) {
            int ci = w + i * 4;
            int row = ci * 8 + lrow;
            __builtin_amdgcn_global_load_lds(
                (const __attribute__((address_space(1))) unsigned int*)
                    (A + (size_t)(bm + row) * DIM + k0 + lcol),
                (__attribute__((address_space(3))) unsigned int*)(As + ci * 8 * 64),
                16, 0, 0);
            __builtin_amdgcn_global_load_lds(
                (const __attribute__((address_space(1))) unsigned int*)
                    (BT + (size_t)(bn + row) * DIM + k0 + lcol),
                (__attribute__((address_space(3))) unsigned int*)(Bs + ci * 8 * 64),
                16, 0, 0);
        }
        __syncthreads();
        #pragma unroll
        for (int kc = 0; kc < 2; kc++) {
            const int ko = kc * 32 + quad * 8;
            s8v af[4], bf[4];
            #pragma unroll
            for (int mi = 0; mi < 4; mi++)
                af[mi] = *(const s8v*)&As[(wm + mi * 16 + l15) * 64 + ko];
            #pragma unroll
            for (int ni = 0; ni < 4; ni++)
                bf[ni] = *(const s8v*)&Bs[(wn + ni * 16 + l15) * 64 + ko];
            #pragma unroll
            for (int mi = 0; mi < 4; mi++)
                #pragma unroll
                for (int ni = 0; ni < 4; ni++)
                    acc[mi][ni] = __builtin_amdgcn_mfma_f32_16x16x32_bf16(
                        af[mi], bf[ni], acc[mi][ni], 0, 0, 0);
        }
    }

    #pragma unroll
    for (int mi = 0; mi < 4; mi++) {
        #pragma unroll
        for (int ni = 0; ni < 4; ni++) {
            if (MODE == 2) {
                // V projection, transposed store: vpT[(b*NH+h)*64+dk][s], r -> s+0..3
                ushort4 o;
                #pragma unroll
                for (int r = 0; r < 4; r++) {
                    int m = bm + wm + mi * 16 + quad * 4 + r;
                    int n = bn + wn + ni * 16 + l15;
                    float val = acc[mi][ni][r] + bias[n];
                    ((unsigned short*)&o)[r] = f2bf(val);
                }
                int m0 = bm + wm + mi * 16 + quad * 4;
                int n = bn + wn + ni * 16 + l15;
                int b = m0 >> 11, s = m0 & (SEQ - 1);
                int h = n >> 6, dk = n & 63;
                *(ushort4*)&((unsigned short*)outp)[(((size_t)(b * NH + h)) * 64 + dk) * SEQ + s] = o;
            } else {
                #pragma unroll
                for (int r = 0; r < 4; r++) {
                    int m = bm + wm + mi * 16 + quad * 4 + r;
                    int n = bn + wn + ni * 16 + l15;
                    float val = acc[mi][ni][r] + bias[n];
                    if (MODE == 0) {
                        ((float*)outp)[(size_t)m * DIM + n] = val;
                    } else {
                        val *= scale;
                        int b = m >> 11, s = m & (SEQ - 1);
                        int h = n >> 6, dk = n & 63;
                        ((unsigned short*)outp)[(((size_t)(b * NH + h)) * SEQ + s) * 64 + dk] = f2bf(val);
                    }
                }
            }
        }
    }
}

// 3 projection GEMMs in one launch (z selects q/k/v); V stored transposed (MODE 2)
__global__ __launch_bounds__(256)
void qkv_gemm(const unsigned short* __restrict__ qb, const unsigned short* __restrict__ kb,
              const unsigned short* __restrict__ vb,
              const unsigned short* __restrict__ WqT, const unsigned short* __restrict__ WkT,
              const unsigned short* __restrict__ WvT,
              const float* __restrict__ bq, const float* __restrict__ bk,
              const float* __restrict__ bv,
              unsigned short* __restrict__ qp, unsigned short* __restrict__ kp,
              unsigned short* __restrict__ vpT)
{
    const int z = blockIdx.z;
    if (z == 0) {
        // fold 1/sqrt(64) AND log2(e) into Q so attention uses exp2 directly
        gemm_core<1>(qb, WqT, bq, qp, 0.18033688011112042f, blockIdx.x, blockIdx.y);
    } else if (z == 1) {
        gemm_core<1>(kb, WkT, bk, kp, 1.0f, blockIdx.x, blockIdx.y);
    } else {
        gemm_core<2>(vb, WvT, bv, vpT, 1.0f, blockIdx.x, blockIdx.y);
    }
}

__global__ __launch_bounds__(256)
void out_gemm(const unsigned short* __restrict__ A, const unsigned short* __restrict__ BT,
              const float* __restrict__ bias, float* __restrict__ outp)
{
    gemm_core<0>(A, BT, bias, outp, 1.0f, blockIdx.x, blockIdx.y);
}

// ---------------- MFMA flash attention v6 ----------------
// Staged structure + async-STAGE split (T14). exp2 via full-rate polynomial
// (fast_exp2) instead of 1/16-rate v_exp_f32. Softmax row-sum l computed on the
// MFMA pipe via ones-vector MFMA (o_l = P*1), which lands l in o_acc's exact
// D-layout -> no cross-lane shuffles in the epilogue. setprio(1) around MFMA.
__global__ __launch_bounds__(256)
void attn_mfma(const unsigned short* __restrict__ Q,
               const unsigned short* __restrict__ Kp,
               const unsigned short* __restrict__ VT,
               unsigned short* __restrict__ AO)
{
    __shared__ __align__(16) unsigned short Ks[64 * 72];     // [key][d]
    __shared__ __align__(16) unsigned short Vs[64 * 72];     // [d][key]
    __shared__ __align__(16) unsigned short Ps[4][32 * 72];  // per-wave P [q][key]
    const int t = threadIdx.x;
    const int lane = t & 63, w = t >> 6;
    const int l15 = lane & 15, quad = lane >> 4;
    const int bh = blockIdx.y, q0 = blockIdx.x * 128;

    const unsigned short* qbase = Q + ((size_t)bh * SEQ + q0 + w * 32) * 64;
    const unsigned short* kbase = Kp + (size_t)bh * SEQ * 64;
    const unsigned short* vtbase = VT + (size_t)bh * 64 * SEQ;

    // Q B-frags: B[n=l15 -> q=qs*16+l15][k=kc*32+quad*8+j -> d]
    s8v qf[2][2];
    #pragma unroll
    for (int qs = 0; qs < 2; qs++)
        #pragma unroll
        for (int kc = 0; kc < 2; kc++)
            qf[qs][kc] = *(const s8v*)&qbase[(qs * 16 + l15) * 64 + kc * 32 + quad * 8];

    f4v o_acc[2][4];   // [qs][df]
    #pragma unroll
    for (int qs = 0; qs < 2; qs++)
        #pragma unroll
        for (int df = 0; df < 4; df++) o_acc[qs][df] = (f4v){0.f, 0.f, 0.f, 0.f};
    f4v o_l[2];        // row-sum accumulators (l = P*ones), same D-layout as o_acc
    o_l[0] = (f4v){0.f, 0.f, 0.f, 0.f};
    o_l[1] = (f4v){0.f, 0.f, 0.f, 0.f};
    const s8v ones = {0x3F80, 0x3F80, 0x3F80, 0x3F80, 0x3F80, 0x3F80, 0x3F80, 0x3F80};

    const int srow = t >> 3, scol = (t & 7) * 8;
    unsigned short* Pw = (unsigned short*)Ps[w];

    // prologue: stage tile 0 (reg round-trip)
    s8v kreg[2], vreg[2];
    #pragma unroll
    for (int i = 0; i < 2; i++) {
        int row = srow + i * 32;
        kreg[i] = *(const s8v*)&kbase[(size_t)row * 64 + scol];
        vreg[i] = *(const s8v*)&vtbase[(size_t)row * SEQ + scol];
    }
    #pragma unroll
    for (int i = 0; i < 2; i++) {
        int row = srow + i * 32;
        *(s8v*)&Ks[row * 72 + scol] = kreg[i];
        *(s8v*)&Vs[row * 72 + scol] = vreg[i];
    }
    __syncthreads();

    for (int kt = 0; kt < 32; kt++) {
        // issue next-tile loads NOW; consumed by ds_write after the post-PV barrier.
        if (kt < 31) {
            #pragma unroll
            for (int i = 0; i < 2; i++) {
                int row = srow + i * 32;
                kreg[i] = *(const s8v*)&kbase[((size_t)((kt + 1) * 64 + row)) * 64 + scol];
                vreg[i] = *(const s8v*)&vtbase[(size_t)row * SEQ + (kt + 1) * 64 + scol];
            }
        }

        // S^T = K*Q^T: A=kf (m=key), B=qf (n=q). Each kf read serves both q-slices.
        f4v s_acc[2][4];   // [qs][mf]: S^T[key=mf*16+quad*4+r][q=qs*16+l15]
        #pragma unroll
        for (int qs = 0; qs < 2; qs++)
            #pragma unroll
            for (int mf = 0; mf < 4; mf++) s_acc[qs][mf] = (f4v){0.f, 0.f, 0.f, 0.f};
        __builtin_amdgcn_s_setprio(1);
        #pragma unroll
        for (int kc = 0; kc < 2; kc++) {
            const int ko = kc * 32 + quad * 8;
            #pragma unroll
            for (int mf = 0; mf < 4; mf++) {
                s8v kf = *(const s8v*)&Ks[(mf * 16 + l15) * 72 + ko];
                #pragma unroll
                for (int qs = 0; qs < 2; qs++)
                    s_acc[qs][mf] = __builtin_amdgcn_mfma_f32_16x16x32_bf16(
                        kf, qf[qs][kc], s_acc[qs][mf], 0, 0, 0);
            }
        }
        __builtin_amdgcn_s_setprio(0);

        // fast exp2 + pack; P stored as b64 (4 consecutive keys per frag)
        #pragma unroll
        for (int qs = 0; qs < 2; qs++) {
            #pragma unroll
            for (int mf = 0; mf < 4; mf++) {
                float p0 = fast_exp2(s_acc[qs][mf][0]);
                float p1 = fast_exp2(s_acc[qs][mf][1]);
                float p2 = fast_exp2(s_acc[qs][mf][2]);
                float p3 = fast_exp2(s_acc[qs][mf][3]);
                uint2 pk;
                pk.x = cvt_pk_bf16(p0, p1);
                pk.y = cvt_pk_bf16(p2, p3);
                *(uint2*)&Pw[(qs * 16 + l15) * 72 + mf * 16 + quad * 4] = pk;
            }
        }

        // O += P*V; l += P*1 (row-sum on the MFMA pipe). Same-wave LDS ordered.
        #pragma unroll
        for (int kc2 = 0; kc2 < 2; kc2++) {
            const int ko = kc2 * 32 + quad * 8;
            s8v pf0 = *(const s8v*)&Pw[(0 * 16 + l15) * 72 + ko];
            s8v pf1 = *(const s8v*)&Pw[(1 * 16 + l15) * 72 + ko];
            __builtin_amdgcn_s_setprio(1);
            o_l[0] = __builtin_amdgcn_mfma_f32_16x16x32_bf16(pf0, ones, o_l[0], 0, 0, 0);
            o_l[1] = __builtin_amdgcn_mfma_f32_16x16x32_bf16(pf1, ones, o_l[1], 0, 0, 0);
            #pragma unroll
            for (int df = 0; df < 4; df++) {
                s8v vf = *(const s8v*)&Vs[(df * 16 + l15) * 72 + ko];
                o_acc[0][df] = __builtin_amdgcn_mfma_f32_16x16x32_bf16(pf0, vf, o_acc[0][df], 0, 0, 0);
                o_acc[1][df] = __builtin_amdgcn_mfma_f32_16x16x32_bf16(pf1, vf, o_acc[1][df], 0, 0, 0);
            }
            __builtin_amdgcn_s_setprio(0);
        }

        __syncthreads();   // all Ks/Vs reads of this tile complete
        if (kt < 31) {
            #pragma unroll
            for (int i = 0; i < 2; i++) {
                int row = srow + i * 32;
                *(s8v*)&Ks[row * 72 + scol] = kreg[i];
                *(s8v*)&Vs[row * 72 + scol] = vreg[i];
            }
        }
        __syncthreads();   // next tile visible
    }

    // o_l[qs][r] is the full row-sum for q = qs*16 + quad*4 + r -- exactly o_acc's
    // row layout, so the divide needs no cross-lane movement.
    const int b = bh >> 4, h = bh & (NH - 1);
    #pragma unroll
    for (int qs = 0; qs < 2; qs++) {
        #pragma unroll
        for (int r = 0; r < 4; r++) {
            float lq = 1.0f / o_l[qs][r];
            int s = q0 + w * 32 + qs * 16 + quad * 4 + r;
            #pragma unroll
            for (int df = 0; df < 4; df++)
                AO[((size_t)(b * SEQ + s)) * DIM + h * 64 + df * 16 + l15] =
                    f2bf(o_acc[qs][df][r] * lq);
        }
    }
}

extern "C" void kernel_launch(void* const* d_in, const int* in_sizes, int n_in,
                              void* d_out, int out_size, void* d_ws, size_t ws_size,
                              hipStream_t stream) {
    const float* q  = (const float*)d_in[0];
    const float* k  = (const float*)d_in[1];
    const float* v  = (const float*)d_in[2];
    const float* Wq = (const float*)d_in[3];
    const float* bq = (const float*)d_in[4];
    const float* Wk = (const float*)d_in[5];
    const float* bk = (const float*)d_in[6];
    const float* Wv = (const float*)d_in[7];
    const float* bv = (const float*)d_in[8];
    const float* Wo = (const float*)d_in[9];
    const float* bo = (const float*)d_in[10];
    float* out = (float*)d_out;

    const size_t MK = (size_t)4 * SEQ * DIM;   // 8M elements
    const size_t WK = (size_t)DIM * DIM;
    unsigned short* wsu = (unsigned short*)d_ws;
    unsigned short* qb  = wsu;
    unsigned short* kb  = qb + MK;
    unsigned short* vb  = kb + MK;
    unsigned short* WqT = vb + MK;
    unsigned short* WkT = WqT + WK;
    unsigned short* WvT = WkT + WK;
    unsigned short* WoT = WvT + WK;
    unsigned short* qp  = WoT + WK;            // bf16 [64][2048][64], pre-scaled log2e/8
    unsigned short* kp  = qp + MK;
    unsigned short* vpT = kp + MK;             // bf16 [64][64][2048] (transposed V, fused)
    unsigned short* ao  = vpT + MK;

    const int n4 = (int)(MK / 4);
    conv3_f32_bf16<<<dim3((n4 + 255) / 256, 3), 256, 0, stream>>>(q, k, v, qb, kb, vb, n4);
    convT4_f32_bf16<<<dim3(16, 16, 4), 256, 0, stream>>>(Wq, Wk, Wv, Wo, WqT, WkT, WvT, WoT);

    qkv_gemm<<<dim3(DIM / 128, (4 * SEQ) / 128, 3), 256, 0, stream>>>(
        qb, kb, vb, WqT, WkT, WvT, bq, bk, bv, qp, kp, vpT);

    attn_mfma<<<dim3(SEQ / 128, 4 * NH), 256, 0, stream>>>(qp, kp, vpT, ao);

    out_gemm<<<dim3(DIM / 128, (4 * SEQ) / 128), 256, 0, stream>>>(ao, WoT, bo, out);
}

// Round 6
// 373.901 us; speedup vs baseline: 1.0575x; 1.0575x over previous
//
#include <hip/hip_runtime.h>
#include <math.h>

#define SEQ 2048
#define DIM 1024
#define NH 16

typedef short s8v __attribute__((ext_vector_type(8)));
typedef short s4v __attribute__((ext_vector_type(4)));
typedef float f4v __attribute__((ext_vector_type(4)));

__device__ __forceinline__ unsigned short f2bf(float x) {   // RNE
    unsigned u = __float_as_uint(x);
    u += 0x7FFFu + ((u >> 16) & 1u);
    return (unsigned short)(u >> 16);
}
__device__ __forceinline__ unsigned cvt_pk_bf16(float lo, float hi) {
    unsigned r;
    asm("v_cvt_pk_bf16_f32 %0, %1, %2" : "=v"(r) : "v"(lo), "v"(hi));
    return r;
}

// ---------------- q,k,v fp32 -> bf16 (one launch) ----------------
__global__ void conv3_f32_bf16(const float* __restrict__ q, const float* __restrict__ k,
                               const float* __restrict__ v,
                               unsigned short* __restrict__ qb, unsigned short* __restrict__ kb,
                               unsigned short* __restrict__ vb, int n4) {
    const float* in = (blockIdx.y == 0) ? q : (blockIdx.y == 1) ? k : v;
    unsigned short* out = (blockIdx.y == 0) ? qb : (blockIdx.y == 1) ? kb : vb;
    int i = blockIdx.x * 256 + threadIdx.x;
    if (i >= n4) return;
    float4 x = ((const float4*)in)[i];
    ushort4 o;
    o.x = f2bf(x.x); o.y = f2bf(x.y); o.z = f2bf(x.z); o.w = f2bf(x.w);
    ((ushort4*)out)[i] = o;
}

// ---------------- 4x W[K,N] fp32 -> WT[N,K] bf16 (one launch) ----------------
__global__ __launch_bounds__(256)
void convT4_f32_bf16(const float* __restrict__ W0, const float* __restrict__ W1,
                     const float* __restrict__ W2, const float* __restrict__ W3,
                     unsigned short* __restrict__ T0, unsigned short* __restrict__ T1,
                     unsigned short* __restrict__ T2, unsigned short* __restrict__ T3) {
    const float* W = (blockIdx.z == 0) ? W0 : (blockIdx.z == 1) ? W1 : (blockIdx.z == 2) ? W2 : W3;
    unsigned short* WT = (blockIdx.z == 0) ? T0 : (blockIdx.z == 1) ? T1 : (blockIdx.z == 2) ? T2 : T3;
    __shared__ float T[64][65];
    const int t = threadIdx.x;
    const int n0 = blockIdx.x * 64, k0 = blockIdx.y * 64;
    #pragma unroll
    for (int i = 0; i < 4; i++) {
        int idx = t + i * 256;
        int r = idx >> 4, c4 = idx & 15;
        float4 v = *(const float4*)&W[(size_t)(k0 + r) * DIM + n0 + c4 * 4];
        T[r][c4 * 4 + 0] = v.x; T[r][c4 * 4 + 1] = v.y;
        T[r][c4 * 4 + 2] = v.z; T[r][c4 * 4 + 3] = v.w;
    }
    __syncthreads();
    #pragma unroll
    for (int i = 0; i < 4; i++) {
        int idx = t + i * 256;
        int rn = idx >> 4, c4 = idx & 15;
        ushort4 o;
        o.x = f2bf(T[c4 * 4 + 0][rn]);
        o.y = f2bf(T[c4 * 4 + 1][rn]);
        o.z = f2bf(T[c4 * 4 + 2][rn]);
        o.w = f2bf(T[c4 * 4 + 3][rn]);
        *(ushort4*)&WT[(size_t)(n0 + rn) * DIM + k0 + c4 * 4] = o;
    }
}

// ---------------- GEMM core (m97 staging), shared by qkv+out projections ----------
// C = A[M,K]*BT[N,K]^T + bias. 128x128 tile, BK=64, global_load_lds staging.
// MODE 0: fp32 out [M,DIM]; MODE 1: bf16 head-split [B,NH,SEQ,64] * scale;
// MODE 2: bf16 head-split TRANSPOSED [B*NH][64][SEQ] (fused V transpose).
template<int MODE>
__device__ __forceinline__
void gemm_core(const unsigned short* __restrict__ A,
               const unsigned short* __restrict__ BT,
               const float* __restrict__ bias, void* __restrict__ outp,
               float scale, int bx, int by)
{
    __shared__ __align__(16) unsigned short As[128 * 64];
    __shared__ __align__(16) unsigned short Bs[128 * 64];
    const int t = threadIdx.x;
    const int lane = t & 63, w = t >> 6;
    const int l15 = lane & 15, quad = lane >> 4;
    const int bm = by * 128, bn = bx * 128;
    const int wm = (w & 1) * 64, wn = (w >> 1) * 64;
    const int lrow = lane >> 3, lcol = (lane & 7) * 8;

    f4v acc[4][4];
    #pragma unroll
    for (int mi = 0; mi < 4; mi++)
        #pragma unroll
        for (int ni = 0; ni < 4; ni++)
            acc[mi][ni] = (f4v){0.f, 0.f, 0.f, 0.f};

    for (int k0 = 0; k0 < DIM; k0 += 64) {
        __syncthreads();
        #pragma unroll
        for (int i = 0; i < 4; i++) {
            int ci = w + i * 4;
            int row = ci * 8 + lrow;
            __builtin_amdgcn_global_load_lds(
                (const __attribute__((address_space(1))) unsigned int*)
                    (A + (size_t)(bm + row) * DIM + k0 + lcol),
                (__attribute__((address_space(3))) unsigned int*)(As + ci * 8 * 64),
                16, 0, 0);
            __builtin_amdgcn_global_load_lds(
                (const __attribute__((address_space(1))) unsigned int*)
                    (BT + (size_t)(bn + row) * DIM + k0 + lcol),
                (__attribute__((address_space(3))) unsigned int*)(Bs + ci * 8 * 64),
                16, 0, 0);
        }
        __syncthreads();
        #pragma unroll
        for (int kc = 0; kc < 2; kc++) {
            const int ko = kc * 32 + quad * 8;
            s8v af[4], bf[4];
            #pragma unroll
            for (int mi = 0; mi < 4; mi++)
                af[mi] = *(const s8v*)&As[(wm + mi * 16 + l15) * 64 + ko];
            #pragma unroll
            for (int ni = 0; ni < 4; ni++)
                bf[ni] = *(const s8v*)&Bs[(wn + ni * 16 + l15) * 64 + ko];
            #pragma unroll
            for (int mi = 0; mi < 4; mi++)
                #pragma unroll
                for (int ni = 0; ni < 4; ni++)
                    acc[mi][ni] = __builtin_amdgcn_mfma_f32_16x16x32_bf16(
                        af[mi], bf[ni], acc[mi][ni], 0, 0, 0);
        }
    }

    #pragma unroll
    for (int mi = 0; mi < 4; mi++) {
        #pragma unroll
        for (int ni = 0; ni < 4; ni++) {
            if (MODE == 2) {
                // V projection, transposed store: vpT[(b*NH+h)*64+dk][s], r -> s+0..3
                ushort4 o;
                #pragma unroll
                for (int r = 0; r < 4; r++) {
                    int m = bm + wm + mi * 16 + quad * 4 + r;
                    int n = bn + wn + ni * 16 + l15;
                    float val = acc[mi][ni][r] + bias[n];
                    ((unsigned short*)&o)[r] = f2bf(val);
                }
                int m0 = bm + wm + mi * 16 + quad * 4;
                int n = bn + wn + ni * 16 + l15;
                int b = m0 >> 11, s = m0 & (SEQ - 1);
                int h = n >> 6, dk = n & 63;
                *(ushort4*)&((unsigned short*)outp)[(((size_t)(b * NH + h)) * 64 + dk) * SEQ + s] = o;
            } else {
                #pragma unroll
                for (int r = 0; r < 4; r++) {
                    int m = bm + wm + mi * 16 + quad * 4 + r;
                    int n = bn + wn + ni * 16 + l15;
                    float val = acc[mi][ni][r] + bias[n];
                    if (MODE == 0) {
                        ((float*)outp)[(size_t)m * DIM + n] = val;
                    } else {
                        val *= scale;
                        int b = m >> 11, s = m & (SEQ - 1);
                        int h = n >> 6, dk = n & 63;
                        ((unsigned short*)outp)[(((size_t)(b * NH + h)) * SEQ + s) * 64 + dk] = f2bf(val);
                    }
                }
            }
        }
    }
}

// 3 projection GEMMs in one launch (z selects q/k/v); V stored transposed (MODE 2)
__global__ __launch_bounds__(256)
void qkv_gemm(const unsigned short* __restrict__ qb, const unsigned short* __restrict__ kb,
              const unsigned short* __restrict__ vb,
              const unsigned short* __restrict__ WqT, const unsigned short* __restrict__ WkT,
              const unsigned short* __restrict__ WvT,
              const float* __restrict__ bq, const float* __restrict__ bk,
              const float* __restrict__ bv,
              unsigned short* __restrict__ qp, unsigned short* __restrict__ kp,
              unsigned short* __restrict__ vpT)
{
    const int z = blockIdx.z;
    if (z == 0) {
        // fold 1/sqrt(64) AND log2(e) into Q so attention uses exp2 directly
        gemm_core<1>(qb, WqT, bq, qp, 0.18033688011112042f, blockIdx.x, blockIdx.y);
    } else if (z == 1) {
        gemm_core<1>(kb, WkT, bk, kp, 1.0f, blockIdx.x, blockIdx.y);
    } else {
        gemm_core<2>(vb, WvT, bv, vpT, 1.0f, blockIdx.x, blockIdx.y);
    }
}

__global__ __launch_bounds__(256)
void out_gemm(const unsigned short* __restrict__ A, const unsigned short* __restrict__ BT,
              const float* __restrict__ bias, float* __restrict__ outp)
{
    gemm_core<0>(A, BT, bias, outp, 1.0f, blockIdx.x, blockIdx.y);
}

// ---------------- MFMA flash attention v9 ----------------
// r5 structure with the P-scratch race closed:
//  (1) P stores go through a short-vector type (bit_cast) so they TBAA-alias the
//      short-vector P fragment reads -- removes the compiler's license to reorder.
//  (2) explicit compile-time fence (asm memory clobber + sched_barrier(0)) between
//      the P-store phase and the PV-read phase -- no ds_read of P can be hoisted
//      above the ds_writes regardless of alias reasoning. Cross-iteration order
//      is already protected by the two __syncthreads.
// Hardware v_exp_f32 (r2-proven), ones-vector MFMA row-sum (r3-proven),
// MODE-2 fused V transpose (r3-proven), async-STAGE split + setprio.
__global__ __launch_bounds__(256)
void attn_mfma(const unsigned short* __restrict__ Q,
               const unsigned short* __restrict__ Kp,
               const unsigned short* __restrict__ VT,
               unsigned short* __restrict__ AO)
{
    __shared__ __align__(16) unsigned short Ks[64 * 72];     // [key][d]
    __shared__ __align__(16) unsigned short Vs[64 * 72];     // [d][key]
    __shared__ __align__(16) unsigned short Ps[4][32 * 72];  // per-wave P [q][key]
    const int t = threadIdx.x;
    const int lane = t & 63, w = t >> 6;
    const int l15 = lane & 15, quad = lane >> 4;
    const int bh = blockIdx.y, q0 = blockIdx.x * 128;

    const unsigned short* qbase = Q + ((size_t)bh * SEQ + q0 + w * 32) * 64;
    const unsigned short* kbase = Kp + (size_t)bh * SEQ * 64;
    const unsigned short* vtbase = VT + (size_t)bh * 64 * SEQ;

    // Q B-frags: B[n=l15 -> q=qs*16+l15][k=kc*32+quad*8+j -> d]
    s8v qf[2][2];
    #pragma unroll
    for (int qs = 0; qs < 2; qs++)
        #pragma unroll
        for (int kc = 0; kc < 2; kc++)
            qf[qs][kc] = *(const s8v*)&qbase[(qs * 16 + l15) * 64 + kc * 32 + quad * 8];

    f4v o_acc[2][4];   // [qs][df]
    #pragma unroll
    for (int qs = 0; qs < 2; qs++)
        #pragma unroll
        for (int df = 0; df < 4; df++) o_acc[qs][df] = (f4v){0.f, 0.f, 0.f, 0.f};
    f4v o_l[2];        // row-sum accumulators (l = P*ones), same D-layout as o_acc
    o_l[0] = (f4v){0.f, 0.f, 0.f, 0.f};
    o_l[1] = (f4v){0.f, 0.f, 0.f, 0.f};
    const s8v ones = {0x3F80, 0x3F80, 0x3F80, 0x3F80, 0x3F80, 0x3F80, 0x3F80, 0x3F80};

    const int srow = t >> 3, scol = (t & 7) * 8;
    unsigned short* Pw = (unsigned short*)Ps[w];

    // prologue: stage tile 0 (reg round-trip)
    s8v kreg[2], vreg[2];
    #pragma unroll
    for (int i = 0; i < 2; i++) {
        int row = srow + i * 32;
        kreg[i] = *(const s8v*)&kbase[(size_t)row * 64 + scol];
        vreg[i] = *(const s8v*)&vtbase[(size_t)row * SEQ + scol];
    }
    #pragma unroll
    for (int i = 0; i < 2; i++) {
        int row = srow + i * 32;
        *(s8v*)&Ks[row * 72 + scol] = kreg[i];
        *(s8v*)&Vs[row * 72 + scol] = vreg[i];
    }
    __syncthreads();

    for (int kt = 0; kt < 32; kt++) {
        // issue next-tile loads NOW; consumed by ds_write after the post-PV barrier.
        if (kt < 31) {
            #pragma unroll
            for (int i = 0; i < 2; i++) {
                int row = srow + i * 32;
                kreg[i] = *(const s8v*)&kbase[((size_t)((kt + 1) * 64 + row)) * 64 + scol];
                vreg[i] = *(const s8v*)&vtbase[(size_t)row * SEQ + (kt + 1) * 64 + scol];
            }
        }

        // S^T = K*Q^T: A=kf (m=key), B=qf (n=q). Each kf read serves both q-slices.
        f4v s_acc[2][4];   // [qs][mf]: S^T[key=mf*16+quad*4+r][q=qs*16+l15]
        #pragma unroll
        for (int qs = 0; qs < 2; qs++)
            #pragma unroll
            for (int mf = 0; mf < 4; mf++) s_acc[qs][mf] = (f4v){0.f, 0.f, 0.f, 0.f};
        __builtin_amdgcn_s_setprio(1);
        #pragma unroll
        for (int kc = 0; kc < 2; kc++) {
            const int ko = kc * 32 + quad * 8;
            #pragma unroll
            for (int mf = 0; mf < 4; mf++) {
                s8v kf = *(const s8v*)&Ks[(mf * 16 + l15) * 72 + ko];
                #pragma unroll
                for (int qs = 0; qs < 2; qs++)
                    s_acc[qs][mf] = __builtin_amdgcn_mfma_f32_16x16x32_bf16(
                        kf, qf[qs][kc], s_acc[qs][mf], 0, 0, 0);
            }
        }
        __builtin_amdgcn_s_setprio(0);

        // hardware exp2 + pack; P stored as b64 through a SHORT-vector type so the
        // stores alias the s8v fragment reads under TBAA.
        #pragma unroll
        for (int qs = 0; qs < 2; qs++) {
            #pragma unroll
            for (int mf = 0; mf < 4; mf++) {
                float p0 = __builtin_amdgcn_exp2f(s_acc[qs][mf][0]);
                float p1 = __builtin_amdgcn_exp2f(s_acc[qs][mf][1]);
                float p2 = __builtin_amdgcn_exp2f(s_acc[qs][mf][2]);
                float p3 = __builtin_amdgcn_exp2f(s_acc[qs][mf][3]);
                uint2 pk;
                pk.x = cvt_pk_bf16(p0, p1);
                pk.y = cvt_pk_bf16(p2, p3);
                *(s4v*)&Pw[(qs * 16 + l15) * 72 + mf * 16 + quad * 4] =
                    __builtin_bit_cast(s4v, pk);
            }
        }

        // FENCE: no PV-phase ds_read of P may move above the P ds_writes.
        asm volatile("" ::: "memory");
        __builtin_amdgcn_sched_barrier(0);

        // O += P*V; l += P*1 (row-sum on the MFMA pipe). Same-wave LDS ordered.
        #pragma unroll
        for (int kc2 = 0; kc2 < 2; kc2++) {
            const int ko = kc2 * 32 + quad * 8;
            s8v pf0 = *(const s8v*)&Pw[(0 * 16 + l15) * 72 + ko];
            s8v pf1 = *(const s8v*)&Pw[(1 * 16 + l15) * 72 + ko];
            __builtin_amdgcn_s_setprio(1);
            o_l[0] = __builtin_amdgcn_mfma_f32_16x16x32_bf16(pf0, ones, o_l[0], 0, 0, 0);
            o_l[1] = __builtin_amdgcn_mfma_f32_16x16x32_bf16(pf1, ones, o_l[1], 0, 0, 0);
            #pragma unroll
            for (int df = 0; df < 4; df++) {
                s8v vf = *(const s8v*)&Vs[(df * 16 + l15) * 72 + ko];
                o_acc[0][df] = __builtin_amdgcn_mfma_f32_16x16x32_bf16(pf0, vf, o_acc[0][df], 0, 0, 0);
                o_acc[1][df] = __builtin_amdgcn_mfma_f32_16x16x32_bf16(pf1, vf, o_acc[1][df], 0, 0, 0);
            }
            __builtin_amdgcn_s_setprio(0);
        }

        __syncthreads();   // all Ks/Vs/Ps reads of this tile complete
        if (kt < 31) {
            #pragma unroll
            for (int i = 0; i < 2; i++) {
                int row = srow + i * 32;
                *(s8v*)&Ks[row * 72 + scol] = kreg[i];
                *(s8v*)&Vs[row * 72 + scol] = vreg[i];
            }
        }
        __syncthreads();   // next tile visible
    }

    // o_l[qs][r] is the full row-sum for q = qs*16 + quad*4 + r -- exactly o_acc's
    // row layout, so the divide needs no cross-lane movement.
    const int b = bh >> 4, h = bh & (NH - 1);
    #pragma unroll
    for (int qs = 0; qs < 2; qs++) {
        #pragma unroll
        for (int r = 0; r < 4; r++) {
            float lq = 1.0f / o_l[qs][r];
            int s = q0 + w * 32 + qs * 16 + quad * 4 + r;
            #pragma unroll
            for (int df = 0; df < 4; df++)
                AO[((size_t)(b * SEQ + s)) * DIM + h * 64 + df * 16 + l15] =
                    f2bf(o_acc[qs][df][r] * lq);
        }
    }
}

extern "C" void kernel_launch(void* const* d_in, const int* in_sizes, int n_in,
                              void* d_out, int out_size, void* d_ws, size_t ws_size,
                              hipStream_t stream) {
    const float* q  = (const float*)d_in[0];
    const float* k  = (const float*)d_in[1];
    const float* v  = (const float*)d_in[2];
    const float* Wq = (const float*)d_in[3];
    const float* bq = (const float*)d_in[4];
    const float* Wk = (const float*)d_in[5];
    const float* bk = (const float*)d_in[6];
    const float* Wv = (const float*)d_in[7];
    const float* bv = (const float*)d_in[8];
    const float* Wo = (const float*)d_in[9];
    const float* bo = (const float*)d_in[10];
    float* out = (float*)d_out;

    const size_t MK = (size_t)4 * SEQ * DIM;   // 8M elements
    const size_t WK = (size_t)DIM * DIM;
    unsigned short* wsu = (unsigned short*)d_ws;
    unsigned short* qb  = wsu;
    unsigned short* kb  = qb + MK;
    unsigned short* vb  = kb + MK;
    unsigned short* WqT = vb + MK;
    unsigned short* WkT = WqT + WK;
    unsigned short* WvT = WkT + WK;
    unsigned short* WoT = WvT + WK;
    unsigned short* qp  = WoT + WK;            // bf16 [64][2048][64], pre-scaled log2e/8
    unsigned short* kp  = qp + MK;
    unsigned short* vpT = kp + MK;             // bf16 [64][64][2048] (transposed V, fused)
    unsigned short* ao  = vpT + MK;

    const int n4 = (int)(MK / 4);
    conv3_f32_bf16<<<dim3((n4 + 255) / 256, 3), 256, 0, stream>>>(q, k, v, qb, kb, vb, n4);
    convT4_f32_bf16<<<dim3(16, 16, 4), 256, 0, stream>>>(Wq, Wk, Wv, Wo, WqT, WkT, WvT, WoT);

    qkv_gemm<<<dim3(DIM / 128, (4 * SEQ) / 128, 3), 256, 0, stream>>>(
        qb, kb, vb, WqT, WkT, WvT, bq, bk, bv, qp, kp, vpT);

    attn_mfma<<<dim3(SEQ / 128, 4 * NH), 256, 0, stream>>>(qp, kp, vpT, ao);

    out_gemm<<<dim3(DIM / 128, (4 * SEQ) / 128), 256, 0, stream>>>(ao, WoT, bo, out);
}

// Round 7
// 367.072 us; speedup vs baseline: 1.0772x; 1.0186x over previous
//
#include <hip/hip_runtime.h>
#include <math.h>

#define SEQ 2048
#define DIM 1024
#define NH 16

typedef short s8v __attribute__((ext_vector_type(8)));
typedef short s4v __attribute__((ext_vector_type(4)));
typedef float f4v __attribute__((ext_vector_type(4)));

__device__ __forceinline__ unsigned short f2bf(float x) {   // RNE
    unsigned u = __float_as_uint(x);
    u += 0x7FFFu + ((u >> 16) & 1u);
    return (unsigned short)(u >> 16);
}
__device__ __forceinline__ unsigned cvt_pk_bf16(float lo, float hi) {
    unsigned r;
    asm("v_cvt_pk_bf16_f32 %0, %1, %2" : "=v"(r) : "v"(lo), "v"(hi));
    return r;
}

// ---------------- fused: q,k,v fp32->bf16  AND  4x W transpose->bf16 ----------------
// blockIdx.y < 3  : conv3 slice y (element block = blockIdx.x)
// blockIdx.y == 3 : convT4, blockIdx.x in [0,1024) decomposed to (bx,by,wz)
__global__ __launch_bounds__(256)
void conv_all(const float* __restrict__ q, const float* __restrict__ k,
              const float* __restrict__ v,
              unsigned short* __restrict__ qb, unsigned short* __restrict__ kb,
              unsigned short* __restrict__ vb, int n4,
              const float* __restrict__ W0, const float* __restrict__ W1,
              const float* __restrict__ W2, const float* __restrict__ W3,
              unsigned short* __restrict__ T0, unsigned short* __restrict__ T1,
              unsigned short* __restrict__ T2, unsigned short* __restrict__ T3)
{
    __shared__ float T[64][65];
    const int t = threadIdx.x;
    if (blockIdx.y < 3) {
        const float* in = (blockIdx.y == 0) ? q : (blockIdx.y == 1) ? k : v;
        unsigned short* out = (blockIdx.y == 0) ? qb : (blockIdx.y == 1) ? kb : vb;
        int i = blockIdx.x * 256 + t;
        if (i >= n4) return;
        float4 x = ((const float4*)in)[i];
        ushort4 o;
        o.x = f2bf(x.x); o.y = f2bf(x.y); o.z = f2bf(x.z); o.w = f2bf(x.w);
        ((ushort4*)out)[i] = o;
        return;
    }
    // convT4 part
    int id = blockIdx.x;
    if (id >= 1024) return;
    const int wz = id >> 8, rem = id & 255;
    const int bxx = rem & 15, byy = rem >> 4;
    const float* W = (wz == 0) ? W0 : (wz == 1) ? W1 : (wz == 2) ? W2 : W3;
    unsigned short* WT = (wz == 0) ? T0 : (wz == 1) ? T1 : (wz == 2) ? T2 : T3;
    const int n0 = bxx * 64, k0 = byy * 64;
    #pragma unroll
    for (int i = 0; i < 4; i++) {
        int idx = t + i * 256;
        int r = idx >> 4, c4 = idx & 15;
        float4 vv = *(const float4*)&W[(size_t)(k0 + r) * DIM + n0 + c4 * 4];
        T[r][c4 * 4 + 0] = vv.x; T[r][c4 * 4 + 1] = vv.y;
        T[r][c4 * 4 + 2] = vv.z; T[r][c4 * 4 + 3] = vv.w;
    }
    __syncthreads();
    #pragma unroll
    for (int i = 0; i < 4; i++) {
        int idx = t + i * 256;
        int rn = idx >> 4, c4 = idx & 15;
        ushort4 o;
        o.x = f2bf(T[c4 * 4 + 0][rn]);
        o.y = f2bf(T[c4 * 4 + 1][rn]);
        o.z = f2bf(T[c4 * 4 + 2][rn]);
        o.w = f2bf(T[c4 * 4 + 3][rn]);
        *(ushort4*)&WT[(size_t)(n0 + rn) * DIM + k0 + c4 * 4] = o;
    }
}

// ---------------- GEMM core (m97 staging), shared by qkv+out projections ----------
// C = A[M,K]*BT[N,K]^T + bias. 128x128 tile, BK=64, global_load_lds staging.
// MODE 0: fp32 out [M,DIM]; MODE 1: bf16 head-split [B,NH,SEQ,64] * scale;
// MODE 2: bf16 head-split TRANSPOSED [B*NH][64][SEQ] (fused V transpose).
template<int MODE>
__device__ __forceinline__
void gemm_core(const unsigned short* __restrict__ A,
               const unsigned short* __restrict__ BT,
               const float* __restrict__ bias, void* __restrict__ outp,
               float scale, int bx, int by)
{
    __shared__ __align__(16) unsigned short As[128 * 64];
    __shared__ __align__(16) unsigned short Bs[128 * 64];
    const int t = threadIdx.x;
    const int lane = t & 63, w = t >> 6;
    const int l15 = lane & 15, quad = lane >> 4;
    const int bm = by * 128, bn = bx * 128;
    const int wm = (w & 1) * 64, wn = (w >> 1) * 64;
    const int lrow = lane >> 3, lcol = (lane & 7) * 8;

    f4v acc[4][4];
    #pragma unroll
    for (int mi = 0; mi < 4; mi++)
        #pragma unroll
        for (int ni = 0; ni < 4; ni++)
            acc[mi][ni] = (f4v){0.f, 0.f, 0.f, 0.f};

    for (int k0 = 0; k0 < DIM; k0 += 64) {
        __syncthreads();
        #pragma unroll
        for (int i = 0; i < 4; i++) {
            int ci = w + i * 4;
            int row = ci * 8 + lrow;
            __builtin_amdgcn_global_load_lds(
                (const __attribute__((address_space(1))) unsigned int*)
                    (A + (size_t)(bm + row) * DIM + k0 + lcol),
                (__attribute__((address_space(3))) unsigned int*)(As + ci * 8 * 64),
                16, 0, 0);
            __builtin_amdgcn_global_load_lds(
                (const __attribute__((address_space(1))) unsigned int*)
                    (BT + (size_t)(bn + row) * DIM + k0 + lcol),
                (__attribute__((address_space(3))) unsigned int*)(Bs + ci * 8 * 64),
                16, 0, 0);
        }
        __syncthreads();
        #pragma unroll
        for (int kc = 0; kc < 2; kc++) {
            const int ko = kc * 32 + quad * 8;
            s8v af[4], bf[4];
            #pragma unroll
            for (int mi = 0; mi < 4; mi++)
                af[mi] = *(const s8v*)&As[(wm + mi * 16 + l15) * 64 + ko];
            #pragma unroll
            for (int ni = 0; ni < 4; ni++)
                bf[ni] = *(const s8v*)&Bs[(wn + ni * 16 + l15) * 64 + ko];
            #pragma unroll
            for (int mi = 0; mi < 4; mi++)
                #pragma unroll
                for (int ni = 0; ni < 4; ni++)
                    acc[mi][ni] = __builtin_amdgcn_mfma_f32_16x16x32_bf16(
                        af[mi], bf[ni], acc[mi][ni], 0, 0, 0);
        }
    }

    #pragma unroll
    for (int mi = 0; mi < 4; mi++) {
        #pragma unroll
        for (int ni = 0; ni < 4; ni++) {
            if (MODE == 2) {
                // V projection, transposed store: vpT[(b*NH+h)*64+dk][s], r -> s+0..3
                ushort4 o;
                #pragma unroll
                for (int r = 0; r < 4; r++) {
                    int m = bm + wm + mi * 16 + quad * 4 + r;
                    int n = bn + wn + ni * 16 + l15;
                    float val = acc[mi][ni][r] + bias[n];
                    ((unsigned short*)&o)[r] = f2bf(val);
                }
                int m0 = bm + wm + mi * 16 + quad * 4;
                int n = bn + wn + ni * 16 + l15;
                int b = m0 >> 11, s = m0 & (SEQ - 1);
                int h = n >> 6, dk = n & 63;
                *(ushort4*)&((unsigned short*)outp)[(((size_t)(b * NH + h)) * 64 + dk) * SEQ + s] = o;
            } else {
                #pragma unroll
                for (int r = 0; r < 4; r++) {
                    int m = bm + wm + mi * 16 + quad * 4 + r;
                    int n = bn + wn + ni * 16 + l15;
                    float val = acc[mi][ni][r] + bias[n];
                    if (MODE == 0) {
                        ((float*)outp)[(size_t)m * DIM + n] = val;
                    } else {
                        val *= scale;
                        int b = m >> 11, s = m & (SEQ - 1);
                        int h = n >> 6, dk = n & 63;
                        ((unsigned short*)outp)[(((size_t)(b * NH + h)) * SEQ + s) * 64 + dk] = f2bf(val);
                    }
                }
            }
        }
    }
}

// XCD-aware bijective swizzle for an (NX x NY) grid dispatched x-fastest.
// Clusters NWG/8 consecutive logical blocks (which share operand panels) per XCD.
template<int NX, int NWG>
__device__ __forceinline__ void xcd_swizzle(int& bx, int& by) {
    const int lin = by * NX + bx;
    const int lin2 = (lin & 7) * (NWG >> 3) + (lin >> 3);
    bx = lin2 % NX;
    by = lin2 / NX;
}

// 3 projection GEMMs in one launch (z selects q/k/v); V stored transposed (MODE 2)
__global__ __launch_bounds__(256)
void qkv_gemm(const unsigned short* __restrict__ qb, const unsigned short* __restrict__ kb,
              const unsigned short* __restrict__ vb,
              const unsigned short* __restrict__ WqT, const unsigned short* __restrict__ WkT,
              const unsigned short* __restrict__ WvT,
              const float* __restrict__ bq, const float* __restrict__ bk,
              const float* __restrict__ bv,
              unsigned short* __restrict__ qp, unsigned short* __restrict__ kp,
              unsigned short* __restrict__ vpT)
{
    int bx = blockIdx.x, by = blockIdx.y;
    xcd_swizzle<8, 512>(bx, by);   // cluster same-A-panel blocks per XCD L2
    const int z = blockIdx.z;
    if (z == 0) {
        // fold 1/sqrt(64) AND log2(e) into Q so attention uses exp2 directly
        gemm_core<1>(qb, WqT, bq, qp, 0.18033688011112042f, bx, by);
    } else if (z == 1) {
        gemm_core<1>(kb, WkT, bk, kp, 1.0f, bx, by);
    } else {
        gemm_core<2>(vb, WvT, bv, vpT, 1.0f, bx, by);
    }
}

__global__ __launch_bounds__(256)
void out_gemm(const unsigned short* __restrict__ A, const unsigned short* __restrict__ BT,
              const float* __restrict__ bias, float* __restrict__ outp)
{
    int bx = blockIdx.x, by = blockIdx.y;
    xcd_swizzle<8, 512>(bx, by);
    gemm_core<0>(A, BT, bias, outp, 1.0f, bx, by);
}

// ---------------- MFMA flash attention v10 ----------------
// = r6 body (race-fixed: short-typed P stores + compile fences) + XCD swizzle:
// the 16 q-blocks sharing one head's K/V (512 KB) are clustered so each XCD's
// L2 holds 8 heads' K/V (4 MB) instead of all XCDs re-fetching everything
// (r6 FETCH 139 MB vs 48 MB logical = 3x overfetch).
__global__ __launch_bounds__(256)
void attn_mfma(const unsigned short* __restrict__ Q,
               const unsigned short* __restrict__ Kp,
               const unsigned short* __restrict__ VT,
               unsigned short* __restrict__ AO)
{
    __shared__ __align__(16) unsigned short Ks[64 * 72];     // [key][d]
    __shared__ __align__(16) unsigned short Vs[64 * 72];     // [d][key]
    __shared__ __align__(16) unsigned short Ps[4][32 * 72];  // per-wave P [q][key]
    const int t = threadIdx.x;
    const int lane = t & 63, w = t >> 6;
    const int l15 = lane & 15, quad = lane >> 4;

    int bxs = blockIdx.x, bys = blockIdx.y;
    xcd_swizzle<16, 1024>(bxs, bys);   // 8 heads (4 MB K/V) per XCD L2
    const int bh = bys, q0 = bxs * 128;

    const unsigned short* qbase = Q + ((size_t)bh * SEQ + q0 + w * 32) * 64;
    const unsigned short* kbase = Kp + (size_t)bh * SEQ * 64;
    const unsigned short* vtbase = VT + (size_t)bh * 64 * SEQ;

    // Q B-frags: B[n=l15 -> q=qs*16+l15][k=kc*32+quad*8+j -> d]
    s8v qf[2][2];
    #pragma unroll
    for (int qs = 0; qs < 2; qs++)
        #pragma unroll
        for (int kc = 0; kc < 2; kc++)
            qf[qs][kc] = *(const s8v*)&qbase[(qs * 16 + l15) * 64 + kc * 32 + quad * 8];

    f4v o_acc[2][4];   // [qs][df]
    #pragma unroll
    for (int qs = 0; qs < 2; qs++)
        #pragma unroll
        for (int df = 0; df < 4; df++) o_acc[qs][df] = (f4v){0.f, 0.f, 0.f, 0.f};
    f4v o_l[2];        // row-sum accumulators (l = P*ones), same D-layout as o_acc
    o_l[0] = (f4v){0.f, 0.f, 0.f, 0.f};
    o_l[1] = (f4v){0.f, 0.f, 0.f, 0.f};
    const s8v ones = {0x3F80, 0x3F80, 0x3F80, 0x3F80, 0x3F80, 0x3F80, 0x3F80, 0x3F80};

    const int srow = t >> 3, scol = (t & 7) * 8;
    unsigned short* Pw = (unsigned short*)Ps[w];

    // prologue: stage tile 0 (reg round-trip)
    s8v kreg[2], vreg[2];
    #pragma unroll
    for (int i = 0; i < 2; i++) {
        int row = srow + i * 32;
        kreg[i] = *(const s8v*)&kbase[(size_t)row * 64 + scol];
        vreg[i] = *(const s8v*)&vtbase[(size_t)row * SEQ + scol];
    }
    #pragma unroll
    for (int i = 0; i < 2; i++) {
        int row = srow + i * 32;
        *(s8v*)&Ks[row * 72 + scol] = kreg[i];
        *(s8v*)&Vs[row * 72 + scol] = vreg[i];
    }
    __syncthreads();

    for (int kt = 0; kt < 32; kt++) {
        // issue next-tile loads NOW; consumed by ds_write after the post-PV barrier.
        if (kt < 31) {
            #pragma unroll
            for (int i = 0; i < 2; i++) {
                int row = srow + i * 32;
                kreg[i] = *(const s8v*)&kbase[((size_t)((kt + 1) * 64 + row)) * 64 + scol];
                vreg[i] = *(const s8v*)&vtbase[(size_t)row * SEQ + (kt + 1) * 64 + scol];
            }
        }

        // S^T = K*Q^T: A=kf (m=key), B=qf (n=q). Each kf read serves both q-slices.
        f4v s_acc[2][4];   // [qs][mf]: S^T[key=mf*16+quad*4+r][q=qs*16+l15]
        #pragma unroll
        for (int qs = 0; qs < 2; qs++)
            #pragma unroll
            for (int mf = 0; mf < 4; mf++) s_acc[qs][mf] = (f4v){0.f, 0.f, 0.f, 0.f};
        __builtin_amdgcn_s_setprio(1);
        #pragma unroll
        for (int kc = 0; kc < 2; kc++) {
            const int ko = kc * 32 + quad * 8;
            #pragma unroll
            for (int mf = 0; mf < 4; mf++) {
                s8v kf = *(const s8v*)&Ks[(mf * 16 + l15) * 72 + ko];
                #pragma unroll
                for (int qs = 0; qs < 2; qs++)
                    s_acc[qs][mf] = __builtin_amdgcn_mfma_f32_16x16x32_bf16(
                        kf, qf[qs][kc], s_acc[qs][mf], 0, 0, 0);
            }
        }
        __builtin_amdgcn_s_setprio(0);

        // hardware exp2 + pack; P stored as b64 through a SHORT-vector type so the
        // stores alias the s8v fragment reads under TBAA.
        #pragma unroll
        for (int qs = 0; qs < 2; qs++) {
            #pragma unroll
            for (int mf = 0; mf < 4; mf++) {
                float p0 = __builtin_amdgcn_exp2f(s_acc[qs][mf][0]);
                float p1 = __builtin_amdgcn_exp2f(s_acc[qs][mf][1]);
                float p2 = __builtin_amdgcn_exp2f(s_acc[qs][mf][2]);
                float p3 = __builtin_amdgcn_exp2f(s_acc[qs][mf][3]);
                uint2 pk;
                pk.x = cvt_pk_bf16(p0, p1);
                pk.y = cvt_pk_bf16(p2, p3);
                *(s4v*)&Pw[(qs * 16 + l15) * 72 + mf * 16 + quad * 4] =
                    __builtin_bit_cast(s4v, pk);
            }
        }

        // FENCE: no PV-phase ds_read of P may move above the P ds_writes.
        asm volatile("" ::: "memory");
        __builtin_amdgcn_sched_barrier(0);

        // O += P*V; l += P*1 (row-sum on the MFMA pipe). Same-wave LDS ordered.
        #pragma unroll
        for (int kc2 = 0; kc2 < 2; kc2++) {
            const int ko = kc2 * 32 + quad * 8;
            s8v pf0 = *(const s8v*)&Pw[(0 * 16 + l15) * 72 + ko];
            s8v pf1 = *(const s8v*)&Pw[(1 * 16 + l15) * 72 + ko];
            __builtin_amdgcn_s_setprio(1);
            o_l[0] = __builtin_amdgcn_mfma_f32_16x16x32_bf16(pf0, ones, o_l[0], 0, 0, 0);
            o_l[1] = __builtin_amdgcn_mfma_f32_16x16x32_bf16(pf1, ones, o_l[1], 0, 0, 0);
            #pragma unroll
            for (int df = 0; df < 4; df++) {
                s8v vf = *(const s8v*)&Vs[(df * 16 + l15) * 72 + ko];
                o_acc[0][df] = __builtin_amdgcn_mfma_f32_16x16x32_bf16(pf0, vf, o_acc[0][df], 0, 0, 0);
                o_acc[1][df] = __builtin_amdgcn_mfma_f32_16x16x32_bf16(pf1, vf, o_acc[1][df], 0, 0, 0);
            }
            __builtin_amdgcn_s_setprio(0);
        }

        __syncthreads();   // all Ks/Vs/Ps reads of this tile complete
        if (kt < 31) {
            #pragma unroll
            for (int i = 0; i < 2; i++) {
                int row = srow + i * 32;
                *(s8v*)&Ks[row * 72 + scol] = kreg[i];
                *(s8v*)&Vs[row * 72 + scol] = vreg[i];
            }
        }
        __syncthreads();   // next tile visible
    }

    // o_l[qs][r] is the full row-sum for q = qs*16 + quad*4 + r -- exactly o_acc's
    // row layout, so the divide needs no cross-lane movement.
    const int b = bh >> 4, h = bh & (NH - 1);
    #pragma unroll
    for (int qs = 0; qs < 2; qs++) {
        #pragma unroll
        for (int r = 0; r < 4; r++) {
            float lq = 1.0f / o_l[qs][r];
            int s = q0 + w * 32 + qs * 16 + quad * 4 + r;
            #pragma unroll
            for (int df = 0; df < 4; df++)
                AO[((size_t)(b * SEQ + s)) * DIM + h * 64 + df * 16 + l15] =
                    f2bf(o_acc[qs][df][r] * lq);
        }
    }
}

extern "C" void kernel_launch(void* const* d_in, const int* in_sizes, int n_in,
                              void* d_out, int out_size, void* d_ws, size_t ws_size,
                              hipStream_t stream) {
    const float* q  = (const float*)d_in[0];
    const float* k  = (const float*)d_in[1];
    const float* v  = (const float*)d_in[2];
    const float* Wq = (const float*)d_in[3];
    const float* bq = (const float*)d_in[4];
    const float* Wk = (const float*)d_in[5];
    const float* bk = (const float*)d_in[6];
    const float* Wv = (const float*)d_in[7];
    const float* bv = (const float*)d_in[8];
    const float* Wo = (const float*)d_in[9];
    const float* bo = (const float*)d_in[10];
    float* out = (float*)d_out;

    const size_t MK = (size_t)4 * SEQ * DIM;   // 8M elements
    const size_t WK = (size_t)DIM * DIM;
    unsigned short* wsu = (unsigned short*)d_ws;
    unsigned short* qb  = wsu;
    unsigned short* kb  = qb + MK;
    unsigned short* vb  = kb + MK;
    unsigned short* WqT = vb + MK;
    unsigned short* WkT = WqT + WK;
    unsigned short* WvT = WkT + WK;
    unsigned short* WoT = WvT + WK;
    unsigned short* qp  = WoT + WK;            // bf16 [64][2048][64], pre-scaled log2e/8
    unsigned short* kp  = qp + MK;
    unsigned short* vpT = kp + MK;             // bf16 [64][64][2048] (transposed V, fused)
    unsigned short* ao  = vpT + MK;

    const int n4 = (int)(MK / 4);
    conv_all<<<dim3((n4 + 255) / 256, 4), 256, 0, stream>>>(
        q, k, v, qb, kb, vb, n4, Wq, Wk, Wv, Wo, WqT, WkT, WvT, WoT);

    qkv_gemm<<<dim3(DIM / 128, (4 * SEQ) / 128, 3), 256, 0, stream>>>(
        qb, kb, vb, WqT, WkT, WvT, bq, bk, bv, qp, kp, vpT);

    attn_mfma<<<dim3(SEQ / 128, 4 * NH), 256, 0, stream>>>(qp, kp, vpT, ao);

    out_gemm<<<dim3(DIM / 128, (4 * SEQ) / 128), 256, 0, stream>>>(ao, WoT, bo, out);
}

// Round 8
// 364.976 us; speedup vs baseline: 1.0833x; 1.0057x over previous
//
#include <hip/hip_runtime.h>
#include <math.h>

#define SEQ 2048
#define DIM 1024
#define NH 16

typedef short s8v __attribute__((ext_vector_type(8)));
typedef short s4v __attribute__((ext_vector_type(4)));
typedef float f4v __attribute__((ext_vector_type(4)));

__device__ __forceinline__ unsigned short f2bf(float x) {   // RNE
    unsigned u = __float_as_uint(x);
    u += 0x7FFFu + ((u >> 16) & 1u);
    return (unsigned short)(u >> 16);
}
__device__ __forceinline__ unsigned cvt_pk_bf16(float lo, float hi) {
    unsigned r;
    asm("v_cvt_pk_bf16_f32 %0, %1, %2" : "=v"(r) : "v"(lo), "v"(hi));
    return r;
}

// ---------------- fused: q,k,v fp32->bf16  AND  4x W transpose->bf16 ----------------
__global__ __launch_bounds__(256)
void conv_all(const float* __restrict__ q, const float* __restrict__ k,
              const float* __restrict__ v,
              unsigned short* __restrict__ qb, unsigned short* __restrict__ kb,
              unsigned short* __restrict__ vb, int n4,
              const float* __restrict__ W0, const float* __restrict__ W1,
              const float* __restrict__ W2, const float* __restrict__ W3,
              unsigned short* __restrict__ T0, unsigned short* __restrict__ T1,
              unsigned short* __restrict__ T2, unsigned short* __restrict__ T3)
{
    __shared__ float T[64][65];
    const int t = threadIdx.x;
    if (blockIdx.y < 3) {
        const float* in = (blockIdx.y == 0) ? q : (blockIdx.y == 1) ? k : v;
        unsigned short* out = (blockIdx.y == 0) ? qb : (blockIdx.y == 1) ? kb : vb;
        int i = blockIdx.x * 256 + t;
        if (i >= n4) return;
        float4 x = ((const float4*)in)[i];
        ushort4 o;
        o.x = f2bf(x.x); o.y = f2bf(x.y); o.z = f2bf(x.z); o.w = f2bf(x.w);
        ((ushort4*)out)[i] = o;
        return;
    }
    int id = blockIdx.x;
    if (id >= 1024) return;
    const int wz = id >> 8, rem = id & 255;
    const int bxx = rem & 15, byy = rem >> 4;
    const float* W = (wz == 0) ? W0 : (wz == 1) ? W1 : (wz == 2) ? W2 : W3;
    unsigned short* WT = (wz == 0) ? T0 : (wz == 1) ? T1 : (wz == 2) ? T2 : T3;
    const int n0 = bxx * 64, k0 = byy * 64;
    #pragma unroll
    for (int i = 0; i < 4; i++) {
        int idx = t + i * 256;
        int r = idx >> 4, c4 = idx & 15;
        float4 vv = *(const float4*)&W[(size_t)(k0 + r) * DIM + n0 + c4 * 4];
        T[r][c4 * 4 + 0] = vv.x; T[r][c4 * 4 + 1] = vv.y;
        T[r][c4 * 4 + 2] = vv.z; T[r][c4 * 4 + 3] = vv.w;
    }
    __syncthreads();
    #pragma unroll
    for (int i = 0; i < 4; i++) {
        int idx = t + i * 256;
        int rn = idx >> 4, c4 = idx & 15;
        ushort4 o;
        o.x = f2bf(T[c4 * 4 + 0][rn]);
        o.y = f2bf(T[c4 * 4 + 1][rn]);
        o.z = f2bf(T[c4 * 4 + 2][rn]);
        o.w = f2bf(T[c4 * 4 + 3][rn]);
        *(ushort4*)&WT[(size_t)(n0 + rn) * DIM + k0 + c4 * 4] = o;
    }
}

// ---------------- GEMM core (m97 staging), shared by qkv+out projections ----------
// C = A[M,K]*BT[N,K]^T + bias. 128x128 tile, BK=64, global_load_lds staging.
// MODE 0: fp32 out [M,DIM] (direct stores);
// MODE 1: bf16 head-split [B,NH,SEQ,64]*scale  -- epilogue via LDS, b128 stores;
// MODE 2: bf16 head-split TRANSPOSED [B*NH][64][SEQ] -- epilogue via LDS, b128 stores.
// After the K-loop, As/Bs are dead; reuse the buffer as a 128x136-padded C tile.
template<int MODE>
__device__ __forceinline__
void gemm_core(const unsigned short* __restrict__ A,
               const unsigned short* __restrict__ BT,
               const float* __restrict__ bias, void* __restrict__ outp,
               float scale, int bx, int by)
{
    __shared__ __align__(16) unsigned short smem[17408];   // 34.8 KB (staging 32 KB / C-tile 34 KB)
    unsigned short* As = smem;
    unsigned short* Bs = smem + 128 * 64;
    const int t = threadIdx.x;
    const int lane = t & 63, w = t >> 6;
    const int l15 = lane & 15, quad = lane >> 4;
    const int bm = by * 128, bn = bx * 128;
    const int wm = (w & 1) * 64, wn = (w >> 1) * 64;
    const int lrow = lane >> 3, lcol = (lane & 7) * 8;

    f4v acc[4][4];
    #pragma unroll
    for (int mi = 0; mi < 4; mi++)
        #pragma unroll
        for (int ni = 0; ni < 4; ni++)
            acc[mi][ni] = (f4v){0.f, 0.f, 0.f, 0.f};

    for (int k0 = 0; k0 < DIM; k0 += 64) {
        __syncthreads();
        #pragma unroll
        for (int i = 0; i < 4; i++) {
            int ci = w + i * 4;
            int row = ci * 8 + lrow;
            __builtin_amdgcn_global_load_lds(
                (const __attribute__((address_space(1))) unsigned int*)
                    (A + (size_t)(bm + row) * DIM + k0 + lcol),
                (__attribute__((address_space(3))) unsigned int*)(As + ci * 8 * 64),
                16, 0, 0);
            __builtin_amdgcn_global_load_lds(
                (const __attribute__((address_space(1))) unsigned int*)
                    (BT + (size_t)(bn + row) * DIM + k0 + lcol),
                (__attribute__((address_space(3))) unsigned int*)(Bs + ci * 8 * 64),
                16, 0, 0);
        }
        __syncthreads();
        #pragma unroll
        for (int kc = 0; kc < 2; kc++) {
            const int ko = kc * 32 + quad * 8;
            s8v af[4], bf[4];
            #pragma unroll
            for (int mi = 0; mi < 4; mi++)
                af[mi] = *(const s8v*)&As[(wm + mi * 16 + l15) * 64 + ko];
            #pragma unroll
            for (int ni = 0; ni < 4; ni++)
                bf[ni] = *(const s8v*)&Bs[(wn + ni * 16 + l15) * 64 + ko];
            #pragma unroll
            for (int mi = 0; mi < 4; mi++)
                #pragma unroll
                for (int ni = 0; ni < 4; ni++)
                    acc[mi][ni] = __builtin_amdgcn_mfma_f32_16x16x32_bf16(
                        af[mi], bf[ni], acc[mi][ni], 0, 0, 0);
        }
    }

    if (MODE == 0) {
        #pragma unroll
        for (int mi = 0; mi < 4; mi++)
            #pragma unroll
            for (int ni = 0; ni < 4; ni++)
                #pragma unroll
                for (int r = 0; r < 4; r++) {
                    int m = bm + wm + mi * 16 + quad * 4 + r;
                    int n = bn + wn + ni * 16 + l15;
                    ((float*)outp)[(size_t)m * DIM + n] = acc[mi][ni][r] + bias[n];
                }
    } else {
        __syncthreads();              // all frag reads of As/Bs done -> reuse as Cs
        unsigned short* Cs = smem;    // [128][136] padded bf16 C tile
        if (MODE == 1) {
            // stage row-major [m][n]
            #pragma unroll
            for (int mi = 0; mi < 4; mi++)
                #pragma unroll
                for (int ni = 0; ni < 4; ni++)
                    #pragma unroll
                    for (int r = 0; r < 4; r++) {
                        int ml = wm + mi * 16 + quad * 4 + r;
                        int nl = wn + ni * 16 + l15;
                        float val = (acc[mi][ni][r] + bias[bn + nl]) * scale;
                        Cs[ml * 136 + nl] = f2bf(val);
                    }
        } else {
            // stage transposed [n][m]; 4 consecutive m per thread -> b64 write
            #pragma unroll
            for (int mi = 0; mi < 4; mi++)
                #pragma unroll
                for (int ni = 0; ni < 4; ni++) {
                    int nl = wn + ni * 16 + l15;
                    int m0 = wm + mi * 16 + quad * 4;
                    s4v o;
                    #pragma unroll
                    for (int r = 0; r < 4; r++)
                        o[r] = (short)f2bf(acc[mi][ni][r] + bias[bn + nl]);
                    *(s4v*)&Cs[nl * 136 + m0] = o;
                }
        }
        __syncthreads();
        // coalesced b128 stores: 8 iters x 256 threads x 8 bf16
        #pragma unroll
        for (int it = 0; it < 8; it++) {
            int idx = t + it * 256;
            int rr = idx >> 4, cc = (idx & 15) * 8;
            if (MODE == 1) {
                int m = bm + rr, n = bn + cc;
                int b = m >> 11, s = m & (SEQ - 1);
                int h = n >> 6, dk = n & 63;
                *(s8v*)&((unsigned short*)outp)[(((size_t)(b * NH + h)) * SEQ + s) * 64 + dk] =
                    *(const s8v*)&Cs[rr * 136 + cc];
            } else {
                int n = bn + rr, m0 = bm + cc;
                int b = m0 >> 11, s = m0 & (SEQ - 1);
                int h = n >> 6, dk = n & 63;
                *(s8v*)&((unsigned short*)outp)[((size_t)(b * NH + h) * 64 + dk) * SEQ + s] =
                    *(const s8v*)&Cs[rr * 136 + cc];
            }
        }
    }
}

// XCD-aware bijective swizzle for an (NX x NY) grid dispatched x-fastest.
template<int NX, int NWG>
__device__ __forceinline__ void xcd_swizzle(int& bx, int& by) {
    const int lin = by * NX + bx;
    const int lin2 = (lin & 7) * (NWG >> 3) + (lin >> 3);
    bx = lin2 % NX;
    by = lin2 / NX;
}

// 3 projection GEMMs in one launch (z selects q/k/v); V stored transposed (MODE 2)
__global__ __launch_bounds__(256)
void qkv_gemm(const unsigned short* __restrict__ qb, const unsigned short* __restrict__ kb,
              const unsigned short* __restrict__ vb,
              const unsigned short* __restrict__ WqT, const unsigned short* __restrict__ WkT,
              const unsigned short* __restrict__ WvT,
              const float* __restrict__ bq, const float* __restrict__ bk,
              const float* __restrict__ bv,
              unsigned short* __restrict__ qp, unsigned short* __restrict__ kp,
              unsigned short* __restrict__ vpT)
{
    int bx = blockIdx.x, by = blockIdx.y;
    xcd_swizzle<8, 512>(bx, by);   // cluster same-A-panel blocks per XCD L2
    const int z = blockIdx.z;
    if (z == 0) {
        // fold 1/sqrt(64) AND log2(e) into Q so attention uses exp2 directly
        gemm_core<1>(qb, WqT, bq, qp, 0.18033688011112042f, bx, by);
    } else if (z == 1) {
        gemm_core<1>(kb, WkT, bk, kp, 1.0f, bx, by);
    } else {
        gemm_core<2>(vb, WvT, bv, vpT, 1.0f, bx, by);
    }
}

__global__ __launch_bounds__(256)
void out_gemm(const unsigned short* __restrict__ A, const unsigned short* __restrict__ BT,
              const float* __restrict__ bias, float* __restrict__ outp)
{
    int bx = blockIdx.x, by = blockIdx.y;
    xcd_swizzle<8, 512>(bx, by);
    gemm_core<0>(A, BT, bias, outp, 1.0f, bx, by);
}

// ---------------- MFMA flash attention v10 (byte-identical to r7 passing version) ---
__global__ __launch_bounds__(256)
void attn_mfma(const unsigned short* __restrict__ Q,
               const unsigned short* __restrict__ Kp,
               const unsigned short* __restrict__ VT,
               unsigned short* __restrict__ AO)
{
    __shared__ __align__(16) unsigned short Ks[64 * 72];     // [key][d]
    __shared__ __align__(16) unsigned short Vs[64 * 72];     // [d][key]
    __shared__ __align__(16) unsigned short Ps[4][32 * 72];  // per-wave P [q][key]
    const int t = threadIdx.x;
    const int lane = t & 63, w = t >> 6;
    const int l15 = lane & 15, quad = lane >> 4;

    int bxs = blockIdx.x, bys = blockIdx.y;
    xcd_swizzle<16, 1024>(bxs, bys);   // 8 heads (4 MB K/V) per XCD L2
    const int bh = bys, q0 = bxs * 128;

    const unsigned short* qbase = Q + ((size_t)bh * SEQ + q0 + w * 32) * 64;
    const unsigned short* kbase = Kp + (size_t)bh * SEQ * 64;
    const unsigned short* vtbase = VT + (size_t)bh * 64 * SEQ;

    // Q B-frags: B[n=l15 -> q=qs*16+l15][k=kc*32+quad*8+j -> d]
    s8v qf[2][2];
    #pragma unroll
    for (int qs = 0; qs < 2; qs++)
        #pragma unroll
        for (int kc = 0; kc < 2; kc++)
            qf[qs][kc] = *(const s8v*)&qbase[(qs * 16 + l15) * 64 + kc * 32 + quad * 8];

    f4v o_acc[2][4];   // [qs][df]
    #pragma unroll
    for (int qs = 0; qs < 2; qs++)
        #pragma unroll
        for (int df = 0; df < 4; df++) o_acc[qs][df] = (f4v){0.f, 0.f, 0.f, 0.f};
    f4v o_l[2];        // row-sum accumulators (l = P*ones), same D-layout as o_acc
    o_l[0] = (f4v){0.f, 0.f, 0.f, 0.f};
    o_l[1] = (f4v){0.f, 0.f, 0.f, 0.f};
    const s8v ones = {0x3F80, 0x3F80, 0x3F80, 0x3F80, 0x3F80, 0x3F80, 0x3F80, 0x3F80};

    const int srow = t >> 3, scol = (t & 7) * 8;
    unsigned short* Pw = (unsigned short*)Ps[w];

    // prologue: stage tile 0 (reg round-trip)
    s8v kreg[2], vreg[2];
    #pragma unroll
    for (int i = 0; i < 2; i++) {
        int row = srow + i * 32;
        kreg[i] = *(const s8v*)&kbase[(size_t)row * 64 + scol];
        vreg[i] = *(const s8v*)&vtbase[(size_t)row * SEQ + scol];
    }
    #pragma unroll
    for (int i = 0; i < 2; i++) {
        int row = srow + i * 32;
        *(s8v*)&Ks[row * 72 + scol] = kreg[i];
        *(s8v*)&Vs[row * 72 + scol] = vreg[i];
    }
    __syncthreads();

    for (int kt = 0; kt < 32; kt++) {
        // issue next-tile loads NOW; consumed by ds_write after the post-PV barrier.
        if (kt < 31) {
            #pragma unroll
            for (int i = 0; i < 2; i++) {
                int row = srow + i * 32;
                kreg[i] = *(const s8v*)&kbase[((size_t)((kt + 1) * 64 + row)) * 64 + scol];
                vreg[i] = *(const s8v*)&vtbase[(size_t)row * SEQ + (kt + 1) * 64 + scol];
            }
        }

        // S^T = K*Q^T: A=kf (m=key), B=qf (n=q). Each kf read serves both q-slices.
        f4v s_acc[2][4];   // [qs][mf]: S^T[key=mf*16+quad*4+r][q=qs*16+l15]
        #pragma unroll
        for (int qs = 0; qs < 2; qs++)
            #pragma unroll
            for (int mf = 0; mf < 4; mf++) s_acc[qs][mf] = (f4v){0.f, 0.f, 0.f, 0.f};
        __builtin_amdgcn_s_setprio(1);
        #pragma unroll
        for (int kc = 0; kc < 2; kc++) {
            const int ko = kc * 32 + quad * 8;
            #pragma unroll
            for (int mf = 0; mf < 4; mf++) {
                s8v kf = *(const s8v*)&Ks[(mf * 16 + l15) * 72 + ko];
                #pragma unroll
                for (int qs = 0; qs < 2; qs++)
                    s_acc[qs][mf] = __builtin_amdgcn_mfma_f32_16x16x32_bf16(
                        kf, qf[qs][kc], s_acc[qs][mf], 0, 0, 0);
            }
        }
        __builtin_amdgcn_s_setprio(0);

        // hardware exp2 + pack; P stored as b64 through a SHORT-vector type so the
        // stores alias the s8v fragment reads under TBAA.
        #pragma unroll
        for (int qs = 0; qs < 2; qs++) {
            #pragma unroll
            for (int mf = 0; mf < 4; mf++) {
                float p0 = __builtin_amdgcn_exp2f(s_acc[qs][mf][0]);
                float p1 = __builtin_amdgcn_exp2f(s_acc[qs][mf][1]);
                float p2 = __builtin_amdgcn_exp2f(s_acc[qs][mf][2]);
                float p3 = __builtin_amdgcn_exp2f(s_acc[qs][mf][3]);
                uint2 pk;
                pk.x = cvt_pk_bf16(p0, p1);
                pk.y = cvt_pk_bf16(p2, p3);
                *(s4v*)&Pw[(qs * 16 + l15) * 72 + mf * 16 + quad * 4] =
                    __builtin_bit_cast(s4v, pk);
            }
        }

        // FENCE: no PV-phase ds_read of P may move above the P ds_writes.
        asm volatile("" ::: "memory");
        __builtin_amdgcn_sched_barrier(0);

        // O += P*V; l += P*1 (row-sum on the MFMA pipe). Same-wave LDS ordered.
        #pragma unroll
        for (int kc2 = 0; kc2 < 2; kc2++) {
            const int ko = kc2 * 32 + quad * 8;
            s8v pf0 = *(const s8v*)&Pw[(0 * 16 + l15) * 72 + ko];
            s8v pf1 = *(const s8v*)&Pw[(1 * 16 + l15) * 72 + ko];
            __builtin_amdgcn_s_setprio(1);
            o_l[0] = __builtin_amdgcn_mfma_f32_16x16x32_bf16(pf0, ones, o_l[0], 0, 0, 0);
            o_l[1] = __builtin_amdgcn_mfma_f32_16x16x32_bf16(pf1, ones, o_l[1], 0, 0, 0);
            #pragma unroll
            for (int df = 0; df < 4; df++) {
                s8v vf = *(const s8v*)&Vs[(df * 16 + l15) * 72 + ko];
                o_acc[0][df] = __builtin_amdgcn_mfma_f32_16x16x32_bf16(pf0, vf, o_acc[0][df], 0, 0, 0);
                o_acc[1][df] = __builtin_amdgcn_mfma_f32_16x16x32_bf16(pf1, vf, o_acc[1][df], 0, 0, 0);
            }
            __builtin_amdgcn_s_setprio(0);
        }

        __syncthreads();   // all Ks/Vs/Ps reads of this tile complete
        if (kt < 31) {
            #pragma unroll
            for (int i = 0; i < 2; i++) {
                int row = srow + i * 32;
                *(s8v*)&Ks[row * 72 + scol] = kreg[i];
                *(s8v*)&Vs[row * 72 + scol] = vreg[i];
            }
        }
        __syncthreads();   // next tile visible
    }

    // o_l[qs][r] is the full row-sum for q = qs*16 + quad*4 + r -- exactly o_acc's
    // row layout, so the divide needs no cross-lane movement.
    const int b = bh >> 4, h = bh & (NH - 1);
    #pragma unroll
    for (int qs = 0; qs < 2; qs++) {
        #pragma unroll
        for (int r = 0; r < 4; r++) {
            float lq = 1.0f / o_l[qs][r];
            int s = q0 + w * 32 + qs * 16 + quad * 4 + r;
            #pragma unroll
            for (int df = 0; df < 4; df++)
                AO[((size_t)(b * SEQ + s)) * DIM + h * 64 + df * 16 + l15] =
                    f2bf(o_acc[qs][df][r] * lq);
        }
    }
}

extern "C" void kernel_launch(void* const* d_in, const int* in_sizes, int n_in,
                              void* d_out, int out_size, void* d_ws, size_t ws_size,
                              hipStream_t stream) {
    const float* q  = (const float*)d_in[0];
    const float* k  = (const float*)d_in[1];
    const float* v  = (const float*)d_in[2];
    const float* Wq = (const float*)d_in[3];
    const float* bq = (const float*)d_in[4];
    const float* Wk = (const float*)d_in[5];
    const float* bk = (const float*)d_in[6];
    const float* Wv = (const float*)d_in[7];
    const float* bv = (const float*)d_in[8];
    const float* Wo = (const float*)d_in[9];
    const float* bo = (const float*)d_in[10];
    float* out = (float*)d_out;

    const size_t MK = (size_t)4 * SEQ * DIM;   // 8M elements
    const size_t WK = (size_t)DIM * DIM;
    unsigned short* wsu = (unsigned short*)d_ws;
    unsigned short* qb  = wsu;
    unsigned short* kb  = qb + MK;
    unsigned short* vb  = kb + MK;
    unsigned short* WqT = vb + MK;
    unsigned short* WkT = WqT + WK;
    unsigned short* WvT = WkT + WK;
    unsigned short* WoT = WvT + WK;
    unsigned short* qp  = WoT + WK;            // bf16 [64][2048][64], pre-scaled log2e/8
    unsigned short* kp  = qp + MK;
    unsigned short* vpT = kp + MK;             // bf16 [64][64][2048] (transposed V, fused)
    unsigned short* ao  = vpT + MK;

    const int n4 = (int)(MK / 4);
    conv_all<<<dim3((n4 + 255) / 256, 4), 256, 0, stream>>>(
        q, k, v, qb, kb, vb, n4, Wq, Wk, Wv, Wo, WqT, WkT, WvT, WoT);

    qkv_gemm<<<dim3(DIM / 128, (4 * SEQ) / 128, 3), 256, 0, stream>>>(
        qb, kb, vb, WqT, WkT, WvT, bq, bk, bv, qp, kp, vpT);

    attn_mfma<<<dim3(SEQ / 128, 4 * NH), 256, 0, stream>>>(qp, kp, vpT, ao);

    out_gemm<<<dim3(DIM / 128, (4 * SEQ) / 128), 256, 0, stream>>>(ao, WoT, bo, out);
}